// Round 1
// baseline (565.869 us; speedup 1.0000x reference)
//
#include <hip/hip_runtime.h>
#include <hip/hip_bf16.h>
#include <stdint.h>

// ---------------------------------------------------------------------------
// SupervisedTEMTransition: logits = clip(g + routed_transition(g), +-1) @ W^T + b
//   B=16384, G_TOTAL=768 (modules 256,256,128,128), A=4, NUM_STATES=4096
//
// This version adds ACTION-SORTED ROUTING:
//   setup:  1-block kernel counts rows per action (wave ballots), builds
//           128-padded segment bases segb[5] + cursors, inits s2o[16896]=-1
//   assign: per-row slot = segment base + rank (wave ballot + 4 atomics/wave);
//           writes slot_of[b] (for prep scatter) and s2o[slot]=b (for epilogues)
//   prep:   gather emb[state[b]] -> A1 row slot_of[b] (bf16); W_cls, D* -> bf16
//   trans:  ONE kernel, grid (6,132): block action-uniform (rows sorted+padded),
//           GEMM vs only the matching D_a  => 4x fewer FLOPs than all-action GEMM.
//           Epilogue: clip(g+delta), scatter fp32 to gnext[orig], bf16 to A2[slot]
//   cls:    logits = A2 @ Wb^T + b, rows scattered back to orig order.
// GEMM core unchanged: 128x128 tile, BK=64, mfma_f32_16x16x32_bf16, 4 waves,
// global_load_lds width=16, XOR-swizzled (pre-swizzled-source) LDS.
// ---------------------------------------------------------------------------

typedef __attribute__((ext_vector_type(8))) short short8;   // 8 x bf16 (4 VGPRs)
typedef __attribute__((ext_vector_type(4))) float floatx4;  // MFMA C/D

__device__ __forceinline__ float bf2f(short s) {
    unsigned int u = ((unsigned int)(unsigned short)s) << 16;
    float f;
    __builtin_memcpy(&f, &u, 4);
    return f;
}
__device__ __forceinline__ short f2bf(float f) {  // round-to-nearest-even
    unsigned int u;
    __builtin_memcpy(&u, &f, 4);
    u = (u + 0x7FFFu + ((u >> 16) & 1u)) >> 16;
    return (short)u;
}

#define GLLDS16(g, l)                                                                     \
    __builtin_amdgcn_global_load_lds((const __attribute__((address_space(1))) void*)(g),  \
                                     (__attribute__((address_space(3))) void*)(l), 16, 0, 0)

#define ROWS_PAD 16896  // 16384 + 4*128 worst-case segment padding

// ---------------------------------------------------------------------------
// setup: count rows per action, build padded segment bases + cursors,
// init s2o = -1. meta: [4..8]=segb[0..4], [9..12]=cursor[0..3].
// ---------------------------------------------------------------------------
__global__ __launch_bounds__(1024) void setup_kernel(const int* __restrict__ act,
                                                     int* __restrict__ meta,
                                                     int* __restrict__ s2o) {
    const int tid = threadIdx.x;
    const int lane = tid & 63;
    const int w = tid >> 6;
    __shared__ int lc[16][4];
    int c0 = 0, c1 = 0, c2 = 0, c3 = 0;
    for (int i = tid; i < 16384; i += 1024) {  // exact: all threads 16 iters
        int a = act[i];
        unsigned long long m0 = __ballot(a == 0);
        unsigned long long m1 = __ballot(a == 1);
        unsigned long long m2 = __ballot(a == 2);
        unsigned long long m3 = __ballot(a == 3);
        if (lane == 0) {
            c0 += __popcll(m0); c1 += __popcll(m1);
            c2 += __popcll(m2); c3 += __popcll(m3);
        }
    }
    if (lane == 0) { lc[w][0] = c0; lc[w][1] = c1; lc[w][2] = c2; lc[w][3] = c3; }
    for (int i = tid; i < ROWS_PAD; i += 1024) s2o[i] = -1;
    __syncthreads();
    if (tid == 0) {
        int base = 0;
        for (int k = 0; k < 4; ++k) {
            int c = 0;
            for (int ww = 0; ww < 16; ++ww) c += lc[ww][k];
            meta[4 + k] = base;   // segb[k]
            meta[9 + k] = base;   // cursor[k]
            base += (c + 127) & ~127;  // pad each segment to 128 rows
        }
        meta[8] = base;           // segb[4] = total padded rows
    }
}

// ---------------------------------------------------------------------------
// assign: slot = cursor[a] (wave-aggregated atomic) + rank-in-wave.
// ---------------------------------------------------------------------------
__global__ __launch_bounds__(256) void assign_kernel(const int* __restrict__ act,
                                                     int* __restrict__ meta,
                                                     int* __restrict__ slot_of,
                                                     int* __restrict__ s2o) {
    const int row = blockIdx.x * 256 + threadIdx.x;  // grid 64x256 == 16384 exact
    const int lane = threadIdx.x & 63;
    const int a = act[row];
    const unsigned long long lt = (1ull << lane) - 1ull;
    int* cursor = meta + 9;
    int slot = 0;
    #pragma unroll
    for (int k = 0; k < 4; ++k) {
        unsigned long long m = __ballot(a == k);
        int c = __popcll(m);
        int gb = 0;
        if (lane == 0 && c) gb = atomicAdd(&cursor[k], c);
        gb = __shfl(gb, 0);
        if (a == k) slot = gb + __popcll(m & lt);
    }
    slot_of[row] = slot;
    s2o[slot] = row;
}

// ---------------------------------------------------------------------------
// prep: one float4 per thread. Regions (float4 units):
//   A1 gather  : [0, 3145728)          16384*768/4  (scattered to sorted slot)
//   W_cls      : [3145728, 3932160)    4096*768/4
//   D0         : [3932160, 3997696)    4*256*256/4
//   D1         : [3997696, 4063232)
//   D2         : [4063232, 4079616)    4*128*128/4
//   D3         : [4079616, 4096000)
// ---------------------------------------------------------------------------
__global__ __launch_bounds__(256) void prep_kernel(
    const int* __restrict__ state, const int* __restrict__ slot_of,
    const float* __restrict__ emb, const float* __restrict__ W,
    const float* __restrict__ D0, const float* __restrict__ D1,
    const float* __restrict__ D2, const float* __restrict__ D3,
    short* __restrict__ A1, short* __restrict__ Wb, short* __restrict__ Db) {
    long e = (long)blockIdx.x * 256 + threadIdx.x;
    const float* src;
    short* dst;
    long di;
    if (e < 3145728L) {
        int b = (int)(e / 192);
        int cc = (int)(e % 192);
        int s = state[b];
        int d = slot_of[b];
        src = emb + (long)s * 768 + cc * 4;
        dst = A1; di = (long)d * 192 + cc;
    } else if (e < 3932160L) {
        long t = e - 3145728L;
        src = W + t * 4; dst = Wb; di = t;
    } else if (e < 3997696L) {
        long t = e - 3932160L;
        src = D0 + t * 4; dst = Db; di = t;
    } else if (e < 4063232L) {
        long t = e - 3997696L;
        src = D1 + t * 4; dst = Db + 262144; di = t;
    } else if (e < 4079616L) {
        long t = e - 4063232L;
        src = D2 + t * 4; dst = Db + 524288; di = t;
    } else {
        long t = e - 4079616L;
        src = D3 + t * 4; dst = Db + 589824; di = t;
    }
    float4 v = *(const float4*)src;
    union { ushort4 u4; short s4[4]; } o;
    o.s4[0] = f2bf(v.x); o.s4[1] = f2bf(v.y);
    o.s4[2] = f2bf(v.z); o.s4[3] = f2bf(v.w);
    *(ushort4*)(dst + di * 4) = o.u4;
}

// ---------------------------------------------------------------------------
// Transition GEMM (merged, action-routed). Grid (6, 132):
//   bx 0..3 -> n=256 modules (f=bx>>1, bn=bx&1); bx 4..5 -> n=128 modules.
// Block rows [bm*128, +128) are action-uniform (sorted + 128-padded), so the
// whole block multiplies against only D_a [n x n]: delta[b,j]=sum_i D[a,j,i]*g[b,i].
// ---------------------------------------------------------------------------
__global__ __launch_bounds__(256) void trans_gemm_kernel(
    const short* __restrict__ A, const short* __restrict__ Db,
    const int* __restrict__ meta, const int* __restrict__ s2o,
    float* __restrict__ gnext, short* __restrict__ A2) {
    __shared__ short Ash[128 * 64];
    __shared__ short Bsh[128 * 64];
    const int bx = blockIdx.x, bm = blockIdx.y;
    int n, bn, coloff;
    long Doff;
    if (bx < 4) {
        n = 256; bn = bx & 1;
        int f = bx >> 1;
        coloff = f * 256; Doff = (long)f * 262144;
    } else {
        n = 128; bn = 0;
        int f = bx - 4;
        coloff = 512 + f * 128; Doff = 524288 + (long)f * 65536;
    }
    const int rowbase = bm * 128;
    const int sb4 = meta[8];
    if (rowbase >= sb4) return;  // beyond padded total (uniform, pre-barrier)
    const int a = (rowbase >= meta[5]) + (rowbase >= meta[6]) + (rowbase >= meta[7]);
    const short* Bm = Db + Doff + (long)a * n * n;

    const int tid = threadIdx.x;
    const int lane = tid & 63;
    const int w = tid >> 6;
    const int wm = w & 1, wn = w >> 1;
    const long arow0 = (long)rowbase;
    const long brow0 = (long)bn * 128;
    const int lrow = lane & 15;
    const int q = lane >> 4;

    floatx4 acc[4][4] = {};

    for (int k0 = 0; k0 < n; k0 += 64) {
        #pragma unroll
        for (int it = 0; it < 4; ++it) {
            int c = it * 256 + tid;      // 16B chunk id: row = c/8, kchunk = c%8
            int r = c >> 3, cc = c & 7;
            int gc = cc ^ (r & 7);       // pre-swizzled source, linear LDS dest
            GLLDS16(A + (arow0 + r) * 768 + coloff + k0 + gc * 8, &Ash[c * 8]);
            GLLDS16(Bm + (brow0 + r) * n + k0 + gc * 8, &Bsh[c * 8]);
        }
        __syncthreads();
        #pragma unroll
        for (int kk = 0; kk < 2; ++kk) {
            short8 af[4], bv[4];
            #pragma unroll
            for (int mi = 0; mi < 4; ++mi) {
                int rr = wm * 64 + mi * 16 + lrow;
                int ch = (kk * 4 + q) ^ (rr & 7);
                af[mi] = *(const short8*)&Ash[rr * 64 + ch * 8];
            }
            #pragma unroll
            for (int ni = 0; ni < 4; ++ni) {
                int rr = wn * 64 + ni * 16 + lrow;
                int ch = (kk * 4 + q) ^ (rr & 7);
                bv[ni] = *(const short8*)&Bsh[rr * 64 + ch * 8];
            }
            #pragma unroll
            for (int mi = 0; mi < 4; ++mi)
                #pragma unroll
                for (int ni = 0; ni < 4; ++ni)
                    acc[mi][ni] = __builtin_amdgcn_mfma_f32_16x16x32_bf16(
                        af[mi], bv[ni], acc[mi][ni], 0, 0, 0);
        }
        __syncthreads();
    }

    const int jb = bn * 128 + wn * 64;   // module-local col base
    const int rowb2 = rowbase + wm * 64;
    #pragma unroll
    for (int mi = 0; mi < 4; ++mi) {
        #pragma unroll
        for (int r = 0; r < 4; ++r) {
            int srow = rowb2 + mi * 16 + q * 4 + r;
            int orig = s2o[srow];
            if (orig >= 0) {
                #pragma unroll
                for (int ni = 0; ni < 4; ++ni) {
                    int jl = jb + ni * 16 + lrow;
                    long sidx = (long)srow * 768 + coloff + jl;
                    float g = bf2f(A[sidx]);
                    float v = g + acc[mi][ni][r];
                    v = fminf(1.0f, fmaxf(-1.0f, v));
                    gnext[(long)orig * 768 + coloff + jl] = v;
                    A2[sidx] = f2bf(v);
                }
            }
        }
    }
}

// ---------------------------------------------------------------------------
// Classifier GEMM: [16896x768](sorted) @ [4096x768]^T + bias -> fp32 scattered
// back to original row order. Grid (32, 132).
// ---------------------------------------------------------------------------
__global__ __launch_bounds__(256) void cls_gemm_kernel(
    const short* __restrict__ A, const short* __restrict__ Bm,
    const float* __restrict__ bias, const int* __restrict__ meta,
    const int* __restrict__ s2o, float* __restrict__ out) {
    __shared__ short Ash[128 * 64];
    __shared__ short Bsh[128 * 64];
    const int bn = blockIdx.x, bm = blockIdx.y;
    const int rowbase = bm * 128;
    if (rowbase >= meta[8]) return;  // fully-padding block (uniform, pre-barrier)
    const int tid = threadIdx.x;
    const int lane = tid & 63;
    const int w = tid >> 6;
    const int wm = w & 1, wn = w >> 1;
    const long arow0 = (long)rowbase;
    const long brow0 = (long)bn * 128;
    const int lrow = lane & 15;
    const int q = lane >> 4;

    floatx4 acc[4][4] = {};

    for (int k0 = 0; k0 < 768; k0 += 64) {
        #pragma unroll
        for (int it = 0; it < 4; ++it) {
            int c = it * 256 + tid;
            int r = c >> 3, cc = c & 7;
            int gc = cc ^ (r & 7);
            GLLDS16(A + (arow0 + r) * 768 + k0 + gc * 8, &Ash[c * 8]);
            GLLDS16(Bm + (brow0 + r) * 768 + k0 + gc * 8, &Bsh[c * 8]);
        }
        __syncthreads();
        #pragma unroll
        for (int kk = 0; kk < 2; ++kk) {
            short8 af[4], bv[4];
            #pragma unroll
            for (int mi = 0; mi < 4; ++mi) {
                int rr = wm * 64 + mi * 16 + lrow;
                int ch = (kk * 4 + q) ^ (rr & 7);
                af[mi] = *(const short8*)&Ash[rr * 64 + ch * 8];
            }
            #pragma unroll
            for (int ni = 0; ni < 4; ++ni) {
                int rr = wn * 64 + ni * 16 + lrow;
                int ch = (kk * 4 + q) ^ (rr & 7);
                bv[ni] = *(const short8*)&Bsh[rr * 64 + ch * 8];
            }
            #pragma unroll
            for (int mi = 0; mi < 4; ++mi)
                #pragma unroll
                for (int ni = 0; ni < 4; ++ni)
                    acc[mi][ni] = __builtin_amdgcn_mfma_f32_16x16x32_bf16(
                        af[mi], bv[ni], acc[mi][ni], 0, 0, 0);
        }
        __syncthreads();
    }

    const int rowb2 = rowbase + wm * 64;
    const int colbase = bn * 128 + wn * 64;
    #pragma unroll
    for (int mi = 0; mi < 4; ++mi) {
        #pragma unroll
        for (int r = 0; r < 4; ++r) {
            int srow = rowb2 + mi * 16 + q * 4 + r;
            int orig = s2o[srow];
            if (orig >= 0) {
                #pragma unroll
                for (int ni = 0; ni < 4; ++ni) {
                    int col = colbase + ni * 16 + lrow;
                    out[(long)orig * 4096 + col] = acc[mi][ni][r] + bias[col];
                }
            }
        }
    }
}

extern "C" void kernel_launch(void* const* d_in, const int* in_sizes, int n_in,
                              void* d_out, int out_size, void* d_ws, size_t ws_size,
                              hipStream_t stream) {
    const int* state  = (const int*)d_in[0];
    const int* act    = (const int*)d_in[1];
    const float* emb  = (const float*)d_in[2];
    const float* W    = (const float*)d_in[3];
    const float* bias = (const float*)d_in[4];
    const float* D0   = (const float*)d_in[5];
    const float* D1   = (const float*)d_in[6];
    const float* D2   = (const float*)d_in[7];
    const float* D3   = (const float*)d_in[8];

    float* logits = (float*)d_out;              // [16384 x 4096]
    float* gnext  = logits + 67108864L;         // [16384 x 768]

    // workspace (shorts, then ints) — total ~59.7 MB
    short* A1 = (short*)d_ws;                   // sorted g bf16   [16896 x 768]
    short* A2 = A1 + 12976128L;                 // sorted g_next   [16896 x 768]
    short* Wb = A2 + 12976128L;                 // W_cls bf16      [4096 x 768]
    short* Db = Wb + 3145728L;                  // D0|D1|D2|D3 bf16 (655360)
    int* meta    = (int*)(Db + 655360);         // [16]: segb @4..8, cursor @9..12
    int* slot_of = meta + 16;                   // [16384] orig row -> sorted slot
    int* s2o     = slot_of + 16384;             // [16896] sorted slot -> orig (-1 pad)

    setup_kernel<<<1, 1024, 0, stream>>>(act, meta, s2o);
    assign_kernel<<<64, 256, 0, stream>>>(act, meta, slot_of, s2o);
    prep_kernel<<<16000, 256, 0, stream>>>(state, slot_of, emb, W, D0, D1, D2, D3,
                                           A1, Wb, Db);
    trans_gemm_kernel<<<dim3(6, 132), 256, 0, stream>>>(A1, Db, meta, s2o, gnext, A2);
    cls_gemm_kernel<<<dim3(32, 132), 256, 0, stream>>>(A2, Wb, bias, meta, s2o, logits);
}

// Round 2
// 527.257 us; speedup vs baseline: 1.0732x; 1.0732x over previous
//
#include <hip/hip_runtime.h>
#include <hip/hip_bf16.h>
#include <stdint.h>

// ---------------------------------------------------------------------------
// SupervisedTEMTransition: logits = clip(g + routed_transition(g), +-1) @ W^T + b
//   B=16384, G_TOTAL=768 (modules 256,256,128,128), A=4, NUM_STATES=4096
//
// Pipeline:
//   setup:  count rows per action (ballots), 128-padded segment bases, s2o=-1
//   assign: per-row sorted slot (wave-aggregated atomics)
//   prep:   gather emb[state] -> A1 (sorted, bf16); W_cls, D* -> bf16
//   trans:  action-uniform 128x128-tile GEMM vs matching D_a only (m97 structure)
//   cls:    NEW: 256x256-tile, BK=32, 4-deep LDS ring, counted vmcnt(8),
//           one raw s_barrier per K-tile (no vmcnt(0) drain in main loop),
//           setprio around MFMA cluster, XCD-swizzled grid.
// ---------------------------------------------------------------------------

typedef __attribute__((ext_vector_type(8))) short short8;   // 8 x bf16 (4 VGPRs)
typedef __attribute__((ext_vector_type(4))) float floatx4;  // MFMA C/D

__device__ __forceinline__ float bf2f(short s) {
    unsigned int u = ((unsigned int)(unsigned short)s) << 16;
    float f;
    __builtin_memcpy(&f, &u, 4);
    return f;
}
__device__ __forceinline__ short f2bf(float f) {  // round-to-nearest-even
    unsigned int u;
    __builtin_memcpy(&u, &f, 4);
    u = (u + 0x7FFFu + ((u >> 16) & 1u)) >> 16;
    return (short)u;
}

#define GLLDS16(g, l)                                                                     \
    __builtin_amdgcn_global_load_lds((const __attribute__((address_space(1))) void*)(g),  \
                                     (__attribute__((address_space(3))) void*)(l), 16, 0, 0)

#define ROWS_PAD 16896  // 16384 + 4*128 worst-case segment padding

// ---------------------------------------------------------------------------
// setup: count rows per action, build padded segment bases + cursors,
// init s2o = -1. meta: [4..8]=segb[0..4], [9..12]=cursor[0..3].
// ---------------------------------------------------------------------------
__global__ __launch_bounds__(1024) void setup_kernel(const int* __restrict__ act,
                                                     int* __restrict__ meta,
                                                     int* __restrict__ s2o) {
    const int tid = threadIdx.x;
    const int lane = tid & 63;
    const int w = tid >> 6;
    __shared__ int lc[16][4];
    int c0 = 0, c1 = 0, c2 = 0, c3 = 0;
    for (int i = tid; i < 16384; i += 1024) {
        int a = act[i];
        unsigned long long m0 = __ballot(a == 0);
        unsigned long long m1 = __ballot(a == 1);
        unsigned long long m2 = __ballot(a == 2);
        unsigned long long m3 = __ballot(a == 3);
        if (lane == 0) {
            c0 += __popcll(m0); c1 += __popcll(m1);
            c2 += __popcll(m2); c3 += __popcll(m3);
        }
    }
    if (lane == 0) { lc[w][0] = c0; lc[w][1] = c1; lc[w][2] = c2; lc[w][3] = c3; }
    for (int i = tid; i < ROWS_PAD; i += 1024) s2o[i] = -1;
    __syncthreads();
    if (tid == 0) {
        int base = 0;
        for (int k = 0; k < 4; ++k) {
            int c = 0;
            for (int ww = 0; ww < 16; ++ww) c += lc[ww][k];
            meta[4 + k] = base;   // segb[k]
            meta[9 + k] = base;   // cursor[k]
            base += (c + 127) & ~127;
        }
        meta[8] = base;           // segb[4] = total padded rows
    }
}

// ---------------------------------------------------------------------------
// assign: slot = cursor[a] (wave-aggregated atomic) + rank-in-wave.
// ---------------------------------------------------------------------------
__global__ __launch_bounds__(256) void assign_kernel(const int* __restrict__ act,
                                                     int* __restrict__ meta,
                                                     int* __restrict__ slot_of,
                                                     int* __restrict__ s2o) {
    const int row = blockIdx.x * 256 + threadIdx.x;
    const int lane = threadIdx.x & 63;
    const int a = act[row];
    const unsigned long long lt = (1ull << lane) - 1ull;
    int* cursor = meta + 9;
    int slot = 0;
    #pragma unroll
    for (int k = 0; k < 4; ++k) {
        unsigned long long m = __ballot(a == k);
        int c = __popcll(m);
        int gb = 0;
        if (lane == 0 && c) gb = atomicAdd(&cursor[k], c);
        gb = __shfl(gb, 0);
        if (a == k) slot = gb + __popcll(m & lt);
    }
    slot_of[row] = slot;
    s2o[slot] = row;
}

// ---------------------------------------------------------------------------
// prep: one float4 per thread. A1 gather scattered to sorted slot.
// ---------------------------------------------------------------------------
__global__ __launch_bounds__(256) void prep_kernel(
    const int* __restrict__ state, const int* __restrict__ slot_of,
    const float* __restrict__ emb, const float* __restrict__ W,
    const float* __restrict__ D0, const float* __restrict__ D1,
    const float* __restrict__ D2, const float* __restrict__ D3,
    short* __restrict__ A1, short* __restrict__ Wb, short* __restrict__ Db) {
    long e = (long)blockIdx.x * 256 + threadIdx.x;
    const float* src;
    short* dst;
    long di;
    if (e < 3145728L) {
        int b = (int)(e / 192);
        int cc = (int)(e % 192);
        int s = state[b];
        int d = slot_of[b];
        src = emb + (long)s * 768 + cc * 4;
        dst = A1; di = (long)d * 192 + cc;
    } else if (e < 3932160L) {
        long t = e - 3145728L;
        src = W + t * 4; dst = Wb; di = t;
    } else if (e < 3997696L) {
        long t = e - 3932160L;
        src = D0 + t * 4; dst = Db; di = t;
    } else if (e < 4063232L) {
        long t = e - 3997696L;
        src = D1 + t * 4; dst = Db + 262144; di = t;
    } else if (e < 4079616L) {
        long t = e - 4063232L;
        src = D2 + t * 4; dst = Db + 524288; di = t;
    } else {
        long t = e - 4079616L;
        src = D3 + t * 4; dst = Db + 589824; di = t;
    }
    float4 v = *(const float4*)src;
    union { ushort4 u4; short s4[4]; } o;
    o.s4[0] = f2bf(v.x); o.s4[1] = f2bf(v.y);
    o.s4[2] = f2bf(v.z); o.s4[3] = f2bf(v.w);
    *(ushort4*)(dst + di * 4) = o.u4;
}

// ---------------------------------------------------------------------------
// Transition GEMM (merged, action-routed). Grid (6, 132). m97 structure
// (K is short: 256/128 -> deep pipeline not worth it here).
// ---------------------------------------------------------------------------
__global__ __launch_bounds__(256) void trans_gemm_kernel(
    const short* __restrict__ A, const short* __restrict__ Db,
    const int* __restrict__ meta, const int* __restrict__ s2o,
    float* __restrict__ gnext, short* __restrict__ A2) {
    __shared__ short Ash[128 * 64];
    __shared__ short Bsh[128 * 64];
    const int bx = blockIdx.x, bm = blockIdx.y;
    int n, bn, coloff;
    long Doff;
    if (bx < 4) {
        n = 256; bn = bx & 1;
        int f = bx >> 1;
        coloff = f * 256; Doff = (long)f * 262144;
    } else {
        n = 128; bn = 0;
        int f = bx - 4;
        coloff = 512 + f * 128; Doff = 524288 + (long)f * 65536;
    }
    const int rowbase = bm * 128;
    const int sb4 = meta[8];
    if (rowbase >= sb4) return;
    const int a = (rowbase >= meta[5]) + (rowbase >= meta[6]) + (rowbase >= meta[7]);
    const short* Bm = Db + Doff + (long)a * n * n;

    const int tid = threadIdx.x;
    const int lane = tid & 63;
    const int w = tid >> 6;
    const int wm = w & 1, wn = w >> 1;
    const long arow0 = (long)rowbase;
    const long brow0 = (long)bn * 128;
    const int lrow = lane & 15;
    const int q = lane >> 4;

    floatx4 acc[4][4] = {};

    for (int k0 = 0; k0 < n; k0 += 64) {
        #pragma unroll
        for (int it = 0; it < 4; ++it) {
            int c = it * 256 + tid;
            int r = c >> 3, cc = c & 7;
            int gc = cc ^ (r & 7);
            GLLDS16(A + (arow0 + r) * 768 + coloff + k0 + gc * 8, &Ash[c * 8]);
            GLLDS16(Bm + (brow0 + r) * n + k0 + gc * 8, &Bsh[c * 8]);
        }
        __syncthreads();
        #pragma unroll
        for (int kk = 0; kk < 2; ++kk) {
            short8 af[4], bv[4];
            #pragma unroll
            for (int mi = 0; mi < 4; ++mi) {
                int rr = wm * 64 + mi * 16 + lrow;
                int ch = (kk * 4 + q) ^ (rr & 7);
                af[mi] = *(const short8*)&Ash[rr * 64 + ch * 8];
            }
            #pragma unroll
            for (int ni = 0; ni < 4; ++ni) {
                int rr = wn * 64 + ni * 16 + lrow;
                int ch = (kk * 4 + q) ^ (rr & 7);
                bv[ni] = *(const short8*)&Bsh[rr * 64 + ch * 8];
            }
            #pragma unroll
            for (int mi = 0; mi < 4; ++mi)
                #pragma unroll
                for (int ni = 0; ni < 4; ++ni)
                    acc[mi][ni] = __builtin_amdgcn_mfma_f32_16x16x32_bf16(
                        af[mi], bv[ni], acc[mi][ni], 0, 0, 0);
        }
        __syncthreads();
    }

    const int jb = bn * 128 + wn * 64;
    const int rowb2 = rowbase + wm * 64;
    #pragma unroll
    for (int mi = 0; mi < 4; ++mi) {
        #pragma unroll
        for (int r = 0; r < 4; ++r) {
            int srow = rowb2 + mi * 16 + q * 4 + r;
            int orig = s2o[srow];
            if (orig >= 0) {
                #pragma unroll
                for (int ni = 0; ni < 4; ++ni) {
                    int jl = jb + ni * 16 + lrow;
                    long sidx = (long)srow * 768 + coloff + jl;
                    float g = bf2f(A[sidx]);
                    float v = g + acc[mi][ni][r];
                    v = fminf(1.0f, fmaxf(-1.0f, v));
                    gnext[(long)orig * 768 + coloff + jl] = v;
                    A2[sidx] = f2bf(v);
                }
            }
        }
    }
}

// ---------------------------------------------------------------------------
// Classifier GEMM: [16896x768](sorted) @ [4096x768]^T + bias -> fp32 scattered
// back to original row order.
//
// 256x256 tile, BK=32, 512 threads (8 waves, 2M x 4N; wave output 128x64).
// LDS: 4-buffer ring x (A 16KB + B 16KB) = 128 KiB. Prefetch distance 2:
// iter t consumes buf[t&3], stages tile t+3 into buf[(t+3)&3] (= buf[(t-1)&3],
// whose reads all completed before this iteration's barrier -> no hazard).
// Counted vmcnt(8) per iter (t+1,t+2 stay in flight); vmcnt never drains to 0
// in the main loop. One raw s_barrier per K-tile. setprio(1) around MFMAs.
// K=768 -> NT=24 tiles. Grid (16,66), XCD-swizzled (1056 % 8 == 0).
// ---------------------------------------------------------------------------
__global__ __launch_bounds__(512) void cls_gemm_kernel(
    const short* __restrict__ A, const short* __restrict__ Bm,
    const float* __restrict__ bias, const int* __restrict__ meta,
    const int* __restrict__ s2o, float* __restrict__ out) {
    __shared__ short lds[4][2][8192];  // [buf][A=0|B=1][256 rows x 32 cols]

    int lin = blockIdx.y * 16 + blockIdx.x;
    lin = (lin & 7) * 132 + (lin >> 3);          // XCD-aware bijective swizzle
    const int bn = lin & 15, bm = lin >> 4;
    const int rowbase = bm * 256;
    if (rowbase >= meta[8]) return;              // all-padding block (uniform)

    const int tid = threadIdx.x;
    const int lane = tid & 63;
    const int w = tid >> 6;
    const int wm = w & 1, wn = w >> 1;           // 2 x 4 wave grid
    const long arow0 = (long)rowbase;
    const long brow0 = (long)bn * 256;
    const int lrow = lane & 15;
    const int q = lane >> 4;

    floatx4 acc[8][4] = {};

    // stage K-tile t into ring buffer b. 4 global_load_lds per thread.
    // LDS slot (r, s) holds global k-chunk s ^ ((r>>1)&3)  (64B-stride swizzle).
    auto STAGE = [&](int t, int b) {
        const int k0 = t * 32;
        #pragma unroll
        for (int it = 0; it < 2; ++it) {
            int c = it * 512 + tid;              // 16B chunk: r = c>>2, s = c&3
            int r = c >> 2, s = c & 3;
            int gc = s ^ ((r >> 1) & 3);
            GLLDS16(A + (arow0 + r) * 768 + k0 + gc * 8, &lds[b][0][c * 8]);
            GLLDS16(Bm + (brow0 + r) * 768 + k0 + gc * 8, &lds[b][1][c * 8]);
        }
    };

    auto COMPUTE = [&](int b) {
        const short* Ab = lds[b][0];
        const short* Bb = lds[b][1];
        short8 af[8], bv[4];
        #pragma unroll
        for (int mi = 0; mi < 8; ++mi) {
            int rr = wm * 128 + mi * 16 + lrow;
            int sl = q ^ ((rr >> 1) & 3);
            af[mi] = *(const short8*)&Ab[rr * 32 + sl * 8];
        }
        #pragma unroll
        for (int ni = 0; ni < 4; ++ni) {
            int rr = wn * 64 + ni * 16 + lrow;
            int sl = q ^ ((rr >> 1) & 3);
            bv[ni] = *(const short8*)&Bb[rr * 32 + sl * 8];
        }
        __builtin_amdgcn_s_setprio(1);
        #pragma unroll
        for (int mi = 0; mi < 8; ++mi)
            #pragma unroll
            for (int ni = 0; ni < 4; ++ni)
                acc[mi][ni] = __builtin_amdgcn_mfma_f32_16x16x32_bf16(
                    af[mi], bv[ni], acc[mi][ni], 0, 0, 0);
        __builtin_amdgcn_s_setprio(0);
    };

    // prologue: 3 tiles in flight
    STAGE(0, 0); STAGE(1, 1); STAGE(2, 2);

    // main loop: tiles 0..21. At iter top: outstanding = {t,t+1,t+2} = 12 loads;
    // vmcnt(8) drains exactly tile t's 4. Barrier publishes tile t to all waves.
    for (int t = 0; t < 22; ++t) {
        asm volatile("s_waitcnt vmcnt(8)" ::: "memory");
        __builtin_amdgcn_s_barrier();
        if (t < 21) STAGE(t + 3, (t + 3) & 3);
        COMPUTE(t & 3);
    }
    // epilogue tiles 22, 23 (shrinking in-flight count)
    asm volatile("s_waitcnt vmcnt(4)" ::: "memory");
    __builtin_amdgcn_s_barrier();
    COMPUTE(22 & 3);
    asm volatile("s_waitcnt vmcnt(0)" ::: "memory");
    __builtin_amdgcn_s_barrier();
    COMPUTE(23 & 3);

    const int rowb2 = rowbase + wm * 128;
    const int colbase = bn * 256 + wn * 64;
    #pragma unroll
    for (int mi = 0; mi < 8; ++mi) {
        #pragma unroll
        for (int r = 0; r < 4; ++r) {
            int srow = rowb2 + mi * 16 + q * 4 + r;
            int orig = s2o[srow];
            if (orig >= 0) {
                #pragma unroll
                for (int ni = 0; ni < 4; ++ni) {
                    int col = colbase + ni * 16 + lrow;
                    out[(long)orig * 4096 + col] = acc[mi][ni][r] + bias[col];
                }
            }
        }
    }
}

extern "C" void kernel_launch(void* const* d_in, const int* in_sizes, int n_in,
                              void* d_out, int out_size, void* d_ws, size_t ws_size,
                              hipStream_t stream) {
    const int* state  = (const int*)d_in[0];
    const int* act    = (const int*)d_in[1];
    const float* emb  = (const float*)d_in[2];
    const float* W    = (const float*)d_in[3];
    const float* bias = (const float*)d_in[4];
    const float* D0   = (const float*)d_in[5];
    const float* D1   = (const float*)d_in[6];
    const float* D2   = (const float*)d_in[7];
    const float* D3   = (const float*)d_in[8];

    float* logits = (float*)d_out;              // [16384 x 4096]
    float* gnext  = logits + 67108864L;         // [16384 x 768]

    short* A1 = (short*)d_ws;                   // sorted g bf16   [16896 x 768]
    short* A2 = A1 + 12976128L;                 // sorted g_next   [16896 x 768]
    short* Wb = A2 + 12976128L;                 // W_cls bf16      [4096 x 768]
    short* Db = Wb + 3145728L;                  // D0|D1|D2|D3 bf16 (655360)
    int* meta    = (int*)(Db + 655360);         // [16]: segb @4..8, cursor @9..12
    int* slot_of = meta + 16;                   // [16384] orig row -> sorted slot
    int* s2o     = slot_of + 16384;             // [16896] sorted slot -> orig (-1 pad)

    setup_kernel<<<1, 1024, 0, stream>>>(act, meta, s2o);
    assign_kernel<<<64, 256, 0, stream>>>(act, meta, slot_of, s2o);
    prep_kernel<<<16000, 256, 0, stream>>>(state, slot_of, emb, W, D0, D1, D2, D3,
                                           A1, Wb, Db);
    trans_gemm_kernel<<<dim3(6, 132), 256, 0, stream>>>(A1, Db, meta, s2o, gnext, A2);
    cls_gemm_kernel<<<dim3(16, 66), 512, 0, stream>>>(A2, Wb, bias, meta, s2o, logits);
}

// Round 3
// 489.249 us; speedup vs baseline: 1.1566x; 1.0777x over previous
//
#include <hip/hip_runtime.h>
#include <hip/hip_bf16.h>
#include <stdint.h>

// ---------------------------------------------------------------------------
// SupervisedTEMTransition: logits = clip(g + routed_transition(g), +-1) @ W^T + b
//   B=16384, G_TOTAL=768 (modules 256,256,128,128), A=4, NUM_STATES=4096
//
// Pipeline:
//   setup:  count rows per action (ballots), 128-padded segment bases, s2o=-1
//   assign: per-row sorted slot (wave-aggregated atomics)
//   prep:   gather emb[state] -> A1 (action-sorted, bf16); W_cls, D* -> bf16
//   trans:  action-uniform 128x128-tile GEMM vs matching D_a only; epilogue
//           scatters BOTH gnext (fp32) and A2 (bf16) back to ORIGINAL rows.
//   cls:    dense unsorted GEMM [16384x768]@[4096x768]^T + bias -> logits.
//           256x256 tile, BK=32, 4-deep LDS ring, counted vmcnt(8), one raw
//           s_barrier per K-tile, setprio around MFMAs, XCD-swizzled grid,
//           1024 blocks = exactly 4/CU (tail-free), coalesced fp32 stores.
// ---------------------------------------------------------------------------

typedef __attribute__((ext_vector_type(8))) short short8;   // 8 x bf16 (4 VGPRs)
typedef __attribute__((ext_vector_type(4))) float floatx4;  // MFMA C/D

__device__ __forceinline__ float bf2f(short s) {
    unsigned int u = ((unsigned int)(unsigned short)s) << 16;
    float f;
    __builtin_memcpy(&f, &u, 4);
    return f;
}
__device__ __forceinline__ short f2bf(float f) {  // round-to-nearest-even
    unsigned int u;
    __builtin_memcpy(&u, &f, 4);
    u = (u + 0x7FFFu + ((u >> 16) & 1u)) >> 16;
    return (short)u;
}

#define GLLDS16(g, l)                                                                     \
    __builtin_amdgcn_global_load_lds((const __attribute__((address_space(1))) void*)(g),  \
                                     (__attribute__((address_space(3))) void*)(l), 16, 0, 0)

#define ROWS_PAD 16896  // 16384 + 4*128 worst-case segment padding

// ---------------------------------------------------------------------------
// setup: count rows per action, build padded segment bases + cursors,
// init s2o = -1. meta: [4..8]=segb[0..4], [9..12]=cursor[0..3].
// ---------------------------------------------------------------------------
__global__ __launch_bounds__(1024) void setup_kernel(const int* __restrict__ act,
                                                     int* __restrict__ meta,
                                                     int* __restrict__ s2o) {
    const int tid = threadIdx.x;
    const int lane = tid & 63;
    const int w = tid >> 6;
    __shared__ int lc[16][4];
    int c0 = 0, c1 = 0, c2 = 0, c3 = 0;
    for (int i = tid; i < 16384; i += 1024) {
        int a = act[i];
        unsigned long long m0 = __ballot(a == 0);
        unsigned long long m1 = __ballot(a == 1);
        unsigned long long m2 = __ballot(a == 2);
        unsigned long long m3 = __ballot(a == 3);
        if (lane == 0) {
            c0 += __popcll(m0); c1 += __popcll(m1);
            c2 += __popcll(m2); c3 += __popcll(m3);
        }
    }
    if (lane == 0) { lc[w][0] = c0; lc[w][1] = c1; lc[w][2] = c2; lc[w][3] = c3; }
    for (int i = tid; i < ROWS_PAD; i += 1024) s2o[i] = -1;
    __syncthreads();
    if (tid == 0) {
        int base = 0;
        for (int k = 0; k < 4; ++k) {
            int c = 0;
            for (int ww = 0; ww < 16; ++ww) c += lc[ww][k];
            meta[4 + k] = base;   // segb[k]
            meta[9 + k] = base;   // cursor[k]
            base += (c + 127) & ~127;
        }
        meta[8] = base;           // segb[4] = total padded rows
    }
}

// ---------------------------------------------------------------------------
// assign: slot = cursor[a] (wave-aggregated atomic) + rank-in-wave.
// ---------------------------------------------------------------------------
__global__ __launch_bounds__(256) void assign_kernel(const int* __restrict__ act,
                                                     int* __restrict__ meta,
                                                     int* __restrict__ slot_of,
                                                     int* __restrict__ s2o) {
    const int row = blockIdx.x * 256 + threadIdx.x;
    const int lane = threadIdx.x & 63;
    const int a = act[row];
    const unsigned long long lt = (1ull << lane) - 1ull;
    int* cursor = meta + 9;
    int slot = 0;
    #pragma unroll
    for (int k = 0; k < 4; ++k) {
        unsigned long long m = __ballot(a == k);
        int c = __popcll(m);
        int gb = 0;
        if (lane == 0 && c) gb = atomicAdd(&cursor[k], c);
        gb = __shfl(gb, 0);
        if (a == k) slot = gb + __popcll(m & lt);
    }
    slot_of[row] = slot;
    s2o[slot] = row;
}

// ---------------------------------------------------------------------------
// prep: one float4 per thread. A1 gather scattered to sorted slot.
// ---------------------------------------------------------------------------
__global__ __launch_bounds__(256) void prep_kernel(
    const int* __restrict__ state, const int* __restrict__ slot_of,
    const float* __restrict__ emb, const float* __restrict__ W,
    const float* __restrict__ D0, const float* __restrict__ D1,
    const float* __restrict__ D2, const float* __restrict__ D3,
    short* __restrict__ A1, short* __restrict__ Wb, short* __restrict__ Db) {
    long e = (long)blockIdx.x * 256 + threadIdx.x;
    const float* src;
    short* dst;
    long di;
    if (e < 3145728L) {
        int b = (int)(e / 192);
        int cc = (int)(e % 192);
        int s = state[b];
        int d = slot_of[b];
        src = emb + (long)s * 768 + cc * 4;
        dst = A1; di = (long)d * 192 + cc;
    } else if (e < 3932160L) {
        long t = e - 3145728L;
        src = W + t * 4; dst = Wb; di = t;
    } else if (e < 3997696L) {
        long t = e - 3932160L;
        src = D0 + t * 4; dst = Db; di = t;
    } else if (e < 4063232L) {
        long t = e - 3997696L;
        src = D1 + t * 4; dst = Db + 262144; di = t;
    } else if (e < 4079616L) {
        long t = e - 4063232L;
        src = D2 + t * 4; dst = Db + 524288; di = t;
    } else {
        long t = e - 4079616L;
        src = D3 + t * 4; dst = Db + 589824; di = t;
    }
    float4 v = *(const float4*)src;
    union { ushort4 u4; short s4[4]; } o;
    o.s4[0] = f2bf(v.x); o.s4[1] = f2bf(v.y);
    o.s4[2] = f2bf(v.z); o.s4[3] = f2bf(v.w);
    *(ushort4*)(dst + di * 4) = o.u4;
}

// ---------------------------------------------------------------------------
// Transition GEMM (merged, action-routed). Grid (6, 132). m97 structure;
// ~5 blocks/CU co-residency hides the per-tile drains (K is short).
// Epilogue scatters gnext (fp32) AND A2 (bf16) to ORIGINAL row order.
// ---------------------------------------------------------------------------
__global__ __launch_bounds__(256) void trans_gemm_kernel(
    const short* __restrict__ A, const short* __restrict__ Db,
    const int* __restrict__ meta, const int* __restrict__ s2o,
    float* __restrict__ gnext, short* __restrict__ A2) {
    __shared__ short Ash[128 * 64];
    __shared__ short Bsh[128 * 64];
    const int bx = blockIdx.x, bm = blockIdx.y;
    int n, bn, coloff;
    long Doff;
    if (bx < 4) {
        n = 256; bn = bx & 1;
        int f = bx >> 1;
        coloff = f * 256; Doff = (long)f * 262144;
    } else {
        n = 128; bn = 0;
        int f = bx - 4;
        coloff = 512 + f * 128; Doff = 524288 + (long)f * 65536;
    }
    const int rowbase = bm * 128;
    const int sb4 = meta[8];
    if (rowbase >= sb4) return;
    const int a = (rowbase >= meta[5]) + (rowbase >= meta[6]) + (rowbase >= meta[7]);
    const short* Bm = Db + Doff + (long)a * n * n;

    const int tid = threadIdx.x;
    const int lane = tid & 63;
    const int w = tid >> 6;
    const int wm = w & 1, wn = w >> 1;
    const long arow0 = (long)rowbase;
    const long brow0 = (long)bn * 128;
    const int lrow = lane & 15;
    const int q = lane >> 4;

    floatx4 acc[4][4] = {};

    for (int k0 = 0; k0 < n; k0 += 64) {
        #pragma unroll
        for (int it = 0; it < 4; ++it) {
            int c = it * 256 + tid;
            int r = c >> 3, cc = c & 7;
            int gc = cc ^ (r & 7);
            GLLDS16(A + (arow0 + r) * 768 + coloff + k0 + gc * 8, &Ash[c * 8]);
            GLLDS16(Bm + (brow0 + r) * n + k0 + gc * 8, &Bsh[c * 8]);
        }
        __syncthreads();
        #pragma unroll
        for (int kk = 0; kk < 2; ++kk) {
            short8 af[4], bv[4];
            #pragma unroll
            for (int mi = 0; mi < 4; ++mi) {
                int rr = wm * 64 + mi * 16 + lrow;
                int ch = (kk * 4 + q) ^ (rr & 7);
                af[mi] = *(const short8*)&Ash[rr * 64 + ch * 8];
            }
            #pragma unroll
            for (int ni = 0; ni < 4; ++ni) {
                int rr = wn * 64 + ni * 16 + lrow;
                int ch = (kk * 4 + q) ^ (rr & 7);
                bv[ni] = *(const short8*)&Bsh[rr * 64 + ch * 8];
            }
            #pragma unroll
            for (int mi = 0; mi < 4; ++mi)
                #pragma unroll
                for (int ni = 0; ni < 4; ++ni)
                    acc[mi][ni] = __builtin_amdgcn_mfma_f32_16x16x32_bf16(
                        af[mi], bv[ni], acc[mi][ni], 0, 0, 0);
        }
        __syncthreads();
    }

    const int jb = bn * 128 + wn * 64;
    const int rowb2 = rowbase + wm * 64;
    #pragma unroll
    for (int mi = 0; mi < 4; ++mi) {
        #pragma unroll
        for (int r = 0; r < 4; ++r) {
            int srow = rowb2 + mi * 16 + q * 4 + r;
            int orig = s2o[srow];
            if (orig >= 0) {
                #pragma unroll
                for (int ni = 0; ni < 4; ++ni) {
                    int jl = jb + ni * 16 + lrow;
                    long sidx = (long)srow * 768 + coloff + jl;
                    long oidx = (long)orig * 768 + coloff + jl;
                    float g = bf2f(A[sidx]);
                    float v = g + acc[mi][ni][r];
                    v = fminf(1.0f, fmaxf(-1.0f, v));
                    gnext[oidx] = v;
                    A2[oidx] = f2bf(v);   // original row order -> dense cls
                }
            }
        }
    }
}

// ---------------------------------------------------------------------------
// Classifier GEMM (dense, unsorted): [16384x768] @ [4096x768]^T + bias.
//
// 256x256 tile, BK=32, 512 threads (8 waves, 2M x 4N; wave output 128x64).
// LDS: 4-buffer ring x (A 16KB + B 16KB) = 128 KiB. Prefetch distance 2:
// iter t consumes buf[t&3], stages tile t+3 into buf[(t+3)&3] (= buf[(t-1)&3],
// whose reads all completed before this iteration's barrier -> no hazard).
// Counted vmcnt(8) per iter; never drains to 0 in the main loop. One raw
// s_barrier per K-tile. setprio(1) around MFMAs. K=768 -> 24 tiles.
// Grid (16,64) = 1024 blocks = exactly 4/CU (tail-free), XCD-swizzled.
// Output writes: 16 lanes x 4B = 64B contiguous, consecutive rows in-order
// (fully coalesced; no s2o indirection).
// ---------------------------------------------------------------------------
__global__ __launch_bounds__(512) void cls_gemm_kernel(
    const short* __restrict__ A, const short* __restrict__ Bm,
    const float* __restrict__ bias, float* __restrict__ out) {
    __shared__ short lds[4][2][8192];  // [buf][A=0|B=1][256 rows x 32 cols]

    int lin = blockIdx.y * 16 + blockIdx.x;
    lin = (lin & 7) * 128 + (lin >> 3);          // XCD-aware bijective swizzle
    const int bn = lin & 15, bm = lin >> 4;

    const int tid = threadIdx.x;
    const int lane = tid & 63;
    const int w = tid >> 6;
    const int wm = w & 1, wn = w >> 1;           // 2 x 4 wave grid
    const long arow0 = (long)bm * 256;
    const long brow0 = (long)bn * 256;
    const int lrow = lane & 15;
    const int q = lane >> 4;

    floatx4 acc[8][4] = {};

    // stage K-tile t into ring buffer b. 4 global_load_lds per thread.
    // LDS slot (r, s) holds global k-chunk s ^ ((r>>1)&3)  (64B-stride swizzle).
    auto STAGE = [&](int t, int b) {
        const int k0 = t * 32;
        #pragma unroll
        for (int it = 0; it < 2; ++it) {
            int c = it * 512 + tid;              // 16B chunk: r = c>>2, s = c&3
            int r = c >> 2, s = c & 3;
            int gc = s ^ ((r >> 1) & 3);
            GLLDS16(A + (arow0 + r) * 768 + k0 + gc * 8, &lds[b][0][c * 8]);
            GLLDS16(Bm + (brow0 + r) * 768 + k0 + gc * 8, &lds[b][1][c * 8]);
        }
    };

    auto COMPUTE = [&](int b) {
        const short* Ab = lds[b][0];
        const short* Bb = lds[b][1];
        short8 af[8], bv[4];
        #pragma unroll
        for (int mi = 0; mi < 8; ++mi) {
            int rr = wm * 128 + mi * 16 + lrow;
            int sl = q ^ ((rr >> 1) & 3);
            af[mi] = *(const short8*)&Ab[rr * 32 + sl * 8];
        }
        #pragma unroll
        for (int ni = 0; ni < 4; ++ni) {
            int rr = wn * 64 + ni * 16 + lrow;
            int sl = q ^ ((rr >> 1) & 3);
            bv[ni] = *(const short8*)&Bb[rr * 32 + sl * 8];
        }
        __builtin_amdgcn_s_setprio(1);
        #pragma unroll
        for (int mi = 0; mi < 8; ++mi)
            #pragma unroll
            for (int ni = 0; ni < 4; ++ni)
                acc[mi][ni] = __builtin_amdgcn_mfma_f32_16x16x32_bf16(
                    af[mi], bv[ni], acc[mi][ni], 0, 0, 0);
        __builtin_amdgcn_s_setprio(0);
    };

    // prologue: 3 tiles in flight
    STAGE(0, 0); STAGE(1, 1); STAGE(2, 2);

    // main loop: tiles 0..21. At iter top: outstanding = {t,t+1,t+2} = 12 loads;
    // vmcnt(8) drains exactly tile t's 4. Barrier publishes tile t to all waves.
    for (int t = 0; t < 22; ++t) {
        asm volatile("s_waitcnt vmcnt(8)" ::: "memory");
        __builtin_amdgcn_s_barrier();
        if (t < 21) STAGE(t + 3, (t + 3) & 3);
        COMPUTE(t & 3);
    }
    // epilogue tiles 22, 23 (shrinking in-flight count)
    asm volatile("s_waitcnt vmcnt(4)" ::: "memory");
    __builtin_amdgcn_s_barrier();
    COMPUTE(22 & 3);
    asm volatile("s_waitcnt vmcnt(0)" ::: "memory");
    __builtin_amdgcn_s_barrier();
    COMPUTE(23 & 3);

    const int rowb2 = bm * 256 + wm * 128;
    const int colbase = bn * 256 + wn * 64;
    #pragma unroll
    for (int mi = 0; mi < 8; ++mi) {
        #pragma unroll
        for (int r = 0; r < 4; ++r) {
            int row = rowb2 + mi * 16 + q * 4 + r;
            #pragma unroll
            for (int ni = 0; ni < 4; ++ni) {
                int col = colbase + ni * 16 + lrow;
                out[(long)row * 4096 + col] = acc[mi][ni][r] + bias[col];
            }
        }
    }
}

extern "C" void kernel_launch(void* const* d_in, const int* in_sizes, int n_in,
                              void* d_out, int out_size, void* d_ws, size_t ws_size,
                              hipStream_t stream) {
    const int* state  = (const int*)d_in[0];
    const int* act    = (const int*)d_in[1];
    const float* emb  = (const float*)d_in[2];
    const float* W    = (const float*)d_in[3];
    const float* bias = (const float*)d_in[4];
    const float* D0   = (const float*)d_in[5];
    const float* D1   = (const float*)d_in[6];
    const float* D2   = (const float*)d_in[7];
    const float* D3   = (const float*)d_in[8];

    float* logits = (float*)d_out;              // [16384 x 4096]
    float* gnext  = logits + 67108864L;         // [16384 x 768]

    short* A1 = (short*)d_ws;                   // sorted g bf16    [16896 x 768]
    short* A2 = A1 + 12976128L;                 // g_next bf16 ORIG [16384 x 768]
    short* Wb = A2 + 12976128L;                 // W_cls bf16       [4096 x 768]
    short* Db = Wb + 3145728L;                  // D0|D1|D2|D3 bf16 (655360)
    int* meta    = (int*)(Db + 655360);         // [16]: segb @4..8, cursor @9..12
    int* slot_of = meta + 16;                   // [16384] orig row -> sorted slot
    int* s2o     = slot_of + 16384;             // [16896] sorted slot -> orig (-1 pad)

    setup_kernel<<<1, 1024, 0, stream>>>(act, meta, s2o);
    assign_kernel<<<64, 256, 0, stream>>>(act, meta, slot_of, s2o);
    prep_kernel<<<16000, 256, 0, stream>>>(state, slot_of, emb, W, D0, D1, D2, D3,
                                           A1, Wb, Db);
    trans_gemm_kernel<<<dim3(6, 132), 256, 0, stream>>>(A1, Db, meta, s2o, gnext, A2);
    cls_gemm_kernel<<<dim3(16, 64), 512, 0, stream>>>(A2, Wb, bias, logits);
}

// Round 4
// 486.639 us; speedup vs baseline: 1.1628x; 1.0054x over previous
//
#include <hip/hip_runtime.h>
#include <hip/hip_bf16.h>
#include <stdint.h>

// ---------------------------------------------------------------------------
// SupervisedTEMTransition: logits = clip(g + routed_transition(g), +-1) @ W^T + b
//   B=16384, G_TOTAL=768 (modules 256,256,128,128), A=4, NUM_STATES=4096
//
// Pipeline:
//   sort:   ONE 1-block kernel: per-action counts (ballots) -> 128-padded
//           segment bases -> slot assignment (LDS cursors); s2o=-1 padding.
//   prep:   gather emb[state] -> A1 (action-sorted, bf16); W_cls, D* -> bf16
//   trans:  action-uniform GEMM vs matching D_a only. NEW: 128x128 tile,
//           BK=32, 4-deep LDS ring, counted vmcnt(8) (never drains to 0 in
//           main loop), one raw s_barrier per K-tile, setprio around MFMAs.
//           Epilogue scatters gnext (fp32) + A2 (bf16) to ORIGINAL rows.
//   cls:    dense unsorted GEMM [16384x768]@[4096x768]^T + bias. 256x256
//           tile, BK=32, ring-4, counted vmcnt(8), 1024 blocks = 4/CU,
//           XCD-swizzled, coalesced stores. (unchanged, verified)
// ---------------------------------------------------------------------------

typedef __attribute__((ext_vector_type(8))) short short8;   // 8 x bf16 (4 VGPRs)
typedef __attribute__((ext_vector_type(4))) float floatx4;  // MFMA C/D

__device__ __forceinline__ float bf2f(short s) {
    unsigned int u = ((unsigned int)(unsigned short)s) << 16;
    float f;
    __builtin_memcpy(&f, &u, 4);
    return f;
}
__device__ __forceinline__ short f2bf(float f) {  // round-to-nearest-even
    unsigned int u;
    __builtin_memcpy(&u, &f, 4);
    u = (u + 0x7FFFu + ((u >> 16) & 1u)) >> 16;
    return (short)u;
}

#define GLLDS16(g, l)                                                                     \
    __builtin_amdgcn_global_load_lds((const __attribute__((address_space(1))) void*)(g),  \
                                     (__attribute__((address_space(3))) void*)(l), 16, 0, 0)

#define ROWS_PAD 16896  // 16384 + 4*128 worst-case segment padding

// ---------------------------------------------------------------------------
// sort: counts -> padded bases -> slots, all in one 1-block kernel.
// meta: [4..8] = segb[0..4]. Cursors live in LDS.
// ---------------------------------------------------------------------------
__global__ __launch_bounds__(1024) void sort_kernel(const int* __restrict__ act,
                                                    int* __restrict__ meta,
                                                    int* __restrict__ slot_of,
                                                    int* __restrict__ s2o) {
    const int tid = threadIdx.x;
    const int lane = tid & 63;
    const int w = tid >> 6;
    __shared__ int lc[16][4];
    __shared__ int cur[4];
    int c0 = 0, c1 = 0, c2 = 0, c3 = 0;
    for (int i = tid; i < 16384; i += 1024) {  // exact 16 iters, no divergence
        int a = act[i];
        unsigned long long m0 = __ballot(a == 0);
        unsigned long long m1 = __ballot(a == 1);
        unsigned long long m2 = __ballot(a == 2);
        unsigned long long m3 = __ballot(a == 3);
        if (lane == 0) {
            c0 += __popcll(m0); c1 += __popcll(m1);
            c2 += __popcll(m2); c3 += __popcll(m3);
        }
    }
    if (lane == 0) { lc[w][0] = c0; lc[w][1] = c1; lc[w][2] = c2; lc[w][3] = c3; }
    for (int i = tid; i < ROWS_PAD; i += 1024) s2o[i] = -1;
    __syncthreads();
    if (tid == 0) {
        int base = 0;
        for (int k = 0; k < 4; ++k) {
            int c = 0;
            for (int ww = 0; ww < 16; ++ww) c += lc[ww][k];
            meta[4 + k] = base;
            cur[k] = base;
            base += (c + 127) & ~127;  // pad each segment to 128 rows
        }
        meta[8] = base;                // total padded rows
    }
    __syncthreads();
    const unsigned long long lt = (1ull << lane) - 1ull;
    for (int i = tid; i < 16384; i += 1024) {
        int a = act[i];
        int slot = 0;
        #pragma unroll
        for (int k = 0; k < 4; ++k) {
            unsigned long long m = __ballot(a == k);
            int c = __popcll(m);
            int gb = 0;
            if (lane == 0 && c) gb = atomicAdd(&cur[k], c);
            gb = __shfl(gb, 0);
            if (a == k) slot = gb + __popcll(m & lt);
        }
        slot_of[i] = slot;
        s2o[slot] = i;
    }
}

// ---------------------------------------------------------------------------
// prep: one float4 per thread. A1 gather scattered to sorted slot.
// ---------------------------------------------------------------------------
__global__ __launch_bounds__(256) void prep_kernel(
    const int* __restrict__ state, const int* __restrict__ slot_of,
    const float* __restrict__ emb, const float* __restrict__ W,
    const float* __restrict__ D0, const float* __restrict__ D1,
    const float* __restrict__ D2, const float* __restrict__ D3,
    short* __restrict__ A1, short* __restrict__ Wb, short* __restrict__ Db) {
    long e = (long)blockIdx.x * 256 + threadIdx.x;
    const float* src;
    short* dst;
    long di;
    if (e < 3145728L) {
        int b = (int)(e / 192);
        int cc = (int)(e % 192);
        int s = state[b];
        int d = slot_of[b];
        src = emb + (long)s * 768 + cc * 4;
        dst = A1; di = (long)d * 192 + cc;
    } else if (e < 3932160L) {
        long t = e - 3145728L;
        src = W + t * 4; dst = Wb; di = t;
    } else if (e < 3997696L) {
        long t = e - 3932160L;
        src = D0 + t * 4; dst = Db; di = t;
    } else if (e < 4063232L) {
        long t = e - 3997696L;
        src = D1 + t * 4; dst = Db + 262144; di = t;
    } else if (e < 4079616L) {
        long t = e - 4063232L;
        src = D2 + t * 4; dst = Db + 524288; di = t;
    } else {
        long t = e - 4079616L;
        src = D3 + t * 4; dst = Db + 589824; di = t;
    }
    float4 v = *(const float4*)src;
    union { ushort4 u4; short s4[4]; } o;
    o.s4[0] = f2bf(v.x); o.s4[1] = f2bf(v.y);
    o.s4[2] = f2bf(v.z); o.s4[3] = f2bf(v.w);
    *(ushort4*)(dst + di * 4) = o.u4;
}

// ---------------------------------------------------------------------------
// Transition GEMM (merged, action-routed, ring-pipelined). Grid (6, 132):
//   bx 0..3 -> n=256 modules (f=bx>>1, bn=bx&1); bx 4..5 -> n=128 modules.
// 128x128 tile, 256 threads (4 waves 2x2, wave 64x64, acc 4x4). BK=32,
// ring-4 LDS (64 KiB -> 2 blocks/CU). NT = n/32 = 8 or 4 K-tiles.
// Counted vmcnt(8) main loop (loads stay in flight across barriers);
// hazard: STAGE(t+3) targets buf[(t-1)&3], whose reads completed before the
// iter-t barrier. Epilogue scatters to ORIGINAL row order.
// ---------------------------------------------------------------------------
__global__ __launch_bounds__(256) void trans_gemm_kernel(
    const short* __restrict__ A, const short* __restrict__ Db,
    const int* __restrict__ meta, const int* __restrict__ s2o,
    float* __restrict__ gnext, short* __restrict__ A2) {
    __shared__ short lds[4][2][4096];  // [buf][A=0|B=1][128 rows x 32 cols] = 64 KiB
    const int bx = blockIdx.x, bm = blockIdx.y;
    int n, bn, coloff;
    long Doff;
    if (bx < 4) {
        n = 256; bn = bx & 1;
        int f = bx >> 1;
        coloff = f * 256; Doff = (long)f * 262144;
    } else {
        n = 128; bn = 0;
        int f = bx - 4;
        coloff = 512 + f * 128; Doff = 524288 + (long)f * 65536;
    }
    const int rowbase = bm * 128;
    if (rowbase >= meta[8]) return;  // uniform per block, before any barrier
    const int a = (rowbase >= meta[5]) + (rowbase >= meta[6]) + (rowbase >= meta[7]);
    const short* Bm = Db + Doff + (long)a * n * n;

    const int tid = threadIdx.x;
    const int lane = tid & 63;
    const int w = tid >> 6;
    const int wm = w & 1, wn = w >> 1;           // 2x2 wave grid
    const long arow0 = (long)rowbase;
    const long brow0 = (long)bn * 128;
    const int lrow = lane & 15;
    const int q = lane >> 4;
    const int NT = n >> 5;                       // 8 (n=256) or 4 (n=128)

    floatx4 acc[4][4] = {};

    // stage K-tile t (32 cols) into ring buf b: 4 gl_lds per thread.
    // LDS slot (r, s) holds global k-chunk s ^ ((r>>1)&3)  (64B-stride swizzle).
    auto STAGE = [&](int t, int b) {
        const int k0 = t * 32;
        #pragma unroll
        for (int it = 0; it < 2; ++it) {
            int c = it * 256 + tid;              // 512 chunks: r = c>>2, s = c&3
            int r = c >> 2, s = c & 3;
            int gc = s ^ ((r >> 1) & 3);
            GLLDS16(A + (arow0 + r) * 768 + coloff + k0 + gc * 8, &lds[b][0][c * 8]);
            GLLDS16(Bm + (brow0 + r) * (long)n + k0 + gc * 8, &lds[b][1][c * 8]);
        }
    };

    auto COMPUTE = [&](int b) {
        const short* Ab = lds[b][0];
        const short* Bb = lds[b][1];
        short8 af[4], bv[4];
        #pragma unroll
        for (int mi = 0; mi < 4; ++mi) {
            int rr = wm * 64 + mi * 16 + lrow;
            int sl = q ^ ((rr >> 1) & 3);
            af[mi] = *(const short8*)&Ab[rr * 32 + sl * 8];
        }
        #pragma unroll
        for (int ni = 0; ni < 4; ++ni) {
            int rr = wn * 64 + ni * 16 + lrow;
            int sl = q ^ ((rr >> 1) & 3);
            bv[ni] = *(const short8*)&Bb[rr * 32 + sl * 8];
        }
        __builtin_amdgcn_s_setprio(1);
        #pragma unroll
        for (int mi = 0; mi < 4; ++mi)
            #pragma unroll
            for (int ni = 0; ni < 4; ++ni)
                acc[mi][ni] = __builtin_amdgcn_mfma_f32_16x16x32_bf16(
                    af[mi], bv[ni], acc[mi][ni], 0, 0, 0);
        __builtin_amdgcn_s_setprio(0);
    };

    // prologue: 3 tiles in flight (NT >= 4 always)
    STAGE(0, 0); STAGE(1, 1); STAGE(2, 2);

    for (int t = 0; t < NT - 2; ++t) {
        asm volatile("s_waitcnt vmcnt(8)" ::: "memory");  // drain tile t only
        __builtin_amdgcn_s_barrier();
        if (t + 3 < NT) STAGE(t + 3, (t + 3) & 3);
        COMPUTE(t & 3);
    }
    asm volatile("s_waitcnt vmcnt(4)" ::: "memory");
    __builtin_amdgcn_s_barrier();
    COMPUTE((NT - 2) & 3);
    asm volatile("s_waitcnt vmcnt(0)" ::: "memory");
    __builtin_amdgcn_s_barrier();
    COMPUTE((NT - 1) & 3);

    const int jb = bn * 128 + wn * 64;
    const int rowb2 = rowbase + wm * 64;
    #pragma unroll
    for (int mi = 0; mi < 4; ++mi) {
        #pragma unroll
        for (int r = 0; r < 4; ++r) {
            int srow = rowb2 + mi * 16 + q * 4 + r;
            int orig = s2o[srow];
            if (orig >= 0) {
                #pragma unroll
                for (int ni = 0; ni < 4; ++ni) {
                    int jl = jb + ni * 16 + lrow;
                    long sidx = (long)srow * 768 + coloff + jl;
                    long oidx = (long)orig * 768 + coloff + jl;
                    float g = bf2f(A[sidx]);
                    float v = g + acc[mi][ni][r];
                    v = fminf(1.0f, fmaxf(-1.0f, v));
                    gnext[oidx] = v;
                    A2[oidx] = f2bf(v);   // original row order -> dense cls
                }
            }
        }
    }
}

// ---------------------------------------------------------------------------
// Classifier GEMM (dense, unsorted): [16384x768] @ [4096x768]^T + bias.
// 256x256 tile, BK=32, 512 threads (8 waves 2Mx4N; wave 128x64). Ring-4 LDS
// (128 KiB), counted vmcnt(8), one s_barrier per K-tile, setprio, K=768 ->
// 24 tiles. Grid (16,64) = 1024 blocks = exactly 4/CU, XCD-swizzled,
// fully coalesced stores. (unchanged from round 2 -- verified)
// ---------------------------------------------------------------------------
__global__ __launch_bounds__(512) void cls_gemm_kernel(
    const short* __restrict__ A, const short* __restrict__ Bm,
    const float* __restrict__ bias, float* __restrict__ out) {
    __shared__ short lds[4][2][8192];  // [buf][A=0|B=1][256 rows x 32 cols]

    int lin = blockIdx.y * 16 + blockIdx.x;
    lin = (lin & 7) * 128 + (lin >> 3);          // XCD-aware bijective swizzle
    const int bn = lin & 15, bm = lin >> 4;

    const int tid = threadIdx.x;
    const int lane = tid & 63;
    const int w = tid >> 6;
    const int wm = w & 1, wn = w >> 1;           // 2 x 4 wave grid
    const long arow0 = (long)bm * 256;
    const long brow0 = (long)bn * 256;
    const int lrow = lane & 15;
    const int q = lane >> 4;

    floatx4 acc[8][4] = {};

    auto STAGE = [&](int t, int b) {
        const int k0 = t * 32;
        #pragma unroll
        for (int it = 0; it < 2; ++it) {
            int c = it * 512 + tid;              // 16B chunk: r = c>>2, s = c&3
            int r = c >> 2, s = c & 3;
            int gc = s ^ ((r >> 1) & 3);
            GLLDS16(A + (arow0 + r) * 768 + k0 + gc * 8, &lds[b][0][c * 8]);
            GLLDS16(Bm + (brow0 + r) * 768 + k0 + gc * 8, &lds[b][1][c * 8]);
        }
    };

    auto COMPUTE = [&](int b) {
        const short* Ab = lds[b][0];
        const short* Bb = lds[b][1];
        short8 af[8], bv[4];
        #pragma unroll
        for (int mi = 0; mi < 8; ++mi) {
            int rr = wm * 128 + mi * 16 + lrow;
            int sl = q ^ ((rr >> 1) & 3);
            af[mi] = *(const short8*)&Ab[rr * 32 + sl * 8];
        }
        #pragma unroll
        for (int ni = 0; ni < 4; ++ni) {
            int rr = wn * 64 + ni * 16 + lrow;
            int sl = q ^ ((rr >> 1) & 3);
            bv[ni] = *(const short8*)&Bb[rr * 32 + sl * 8];
        }
        __builtin_amdgcn_s_setprio(1);
        #pragma unroll
        for (int mi = 0; mi < 8; ++mi)
            #pragma unroll
            for (int ni = 0; ni < 4; ++ni)
                acc[mi][ni] = __builtin_amdgcn_mfma_f32_16x16x32_bf16(
                    af[mi], bv[ni], acc[mi][ni], 0, 0, 0);
        __builtin_amdgcn_s_setprio(0);
    };

    STAGE(0, 0); STAGE(1, 1); STAGE(2, 2);

    for (int t = 0; t < 22; ++t) {
        asm volatile("s_waitcnt vmcnt(8)" ::: "memory");
        __builtin_amdgcn_s_barrier();
        if (t < 21) STAGE(t + 3, (t + 3) & 3);
        COMPUTE(t & 3);
    }
    asm volatile("s_waitcnt vmcnt(4)" ::: "memory");
    __builtin_amdgcn_s_barrier();
    COMPUTE(22 & 3);
    asm volatile("s_waitcnt vmcnt(0)" ::: "memory");
    __builtin_amdgcn_s_barrier();
    COMPUTE(23 & 3);

    const int rowb2 = bm * 256 + wm * 128;
    const int colbase = bn * 256 + wn * 64;
    #pragma unroll
    for (int mi = 0; mi < 8; ++mi) {
        #pragma unroll
        for (int r = 0; r < 4; ++r) {
            int row = rowb2 + mi * 16 + q * 4 + r;
            #pragma unroll
            for (int ni = 0; ni < 4; ++ni) {
                int col = colbase + ni * 16 + lrow;
                out[(long)row * 4096 + col] = acc[mi][ni][r] + bias[col];
            }
        }
    }
}

extern "C" void kernel_launch(void* const* d_in, const int* in_sizes, int n_in,
                              void* d_out, int out_size, void* d_ws, size_t ws_size,
                              hipStream_t stream) {
    const int* state  = (const int*)d_in[0];
    const int* act    = (const int*)d_in[1];
    const float* emb  = (const float*)d_in[2];
    const float* W    = (const float*)d_in[3];
    const float* bias = (const float*)d_in[4];
    const float* D0   = (const float*)d_in[5];
    const float* D1   = (const float*)d_in[6];
    const float* D2   = (const float*)d_in[7];
    const float* D3   = (const float*)d_in[8];

    float* logits = (float*)d_out;              // [16384 x 4096]
    float* gnext  = logits + 67108864L;         // [16384 x 768]

    short* A1 = (short*)d_ws;                   // sorted g bf16    [16896 x 768]
    short* A2 = A1 + 12976128L;                 // g_next bf16 ORIG [16384 x 768]
    short* Wb = A2 + 12976128L;                 // W_cls bf16       [4096 x 768]
    short* Db = Wb + 3145728L;                  // D0|D1|D2|D3 bf16 (655360)
    int* meta    = (int*)(Db + 655360);         // [16]: segb @4..8
    int* slot_of = meta + 16;                   // [16384] orig row -> sorted slot
    int* s2o     = slot_of + 16384;             // [16896] sorted slot -> orig (-1 pad)

    sort_kernel<<<1, 1024, 0, stream>>>(act, meta, slot_of, s2o);
    prep_kernel<<<16000, 256, 0, stream>>>(state, slot_of, emb, W, D0, D1, D2, D3,
                                           A1, Wb, Db);
    trans_gemm_kernel<<<dim3(6, 132), 256, 0, stream>>>(A1, Db, meta, s2o, gnext, A2);
    cls_gemm_kernel<<<dim3(16, 64), 512, 0, stream>>>(A2, Wb, bias, logits);
}